// Round 6
// baseline (102.527 us; speedup 1.0000x reference)
//
#include <hip/hip_runtime.h>
#include <hip/hip_cooperative_groups.h>
#include <math.h>

namespace cg = cooperative_groups;

#define SEQ 8192
#define DIM 512  // 2*HIDDEN

typedef float floatx4 __attribute__((ext_vector_type(4)));

// Single cooperative kernel, 1024 blocks x 256 threads (4 blocks/CU, all
// co-resident).
// Phase 1: block b computes exp(a) for its 8 rows (wave v handles rows
//          8b+2v, 8b+2v+1; lane reads 8 contiguous floats). Exps stay in LDS;
//          one partial sum per block goes to global.
//          Max-subtraction skipped: |a| <= sum|w| (~13 worst case), expf is
//          safely in fp32 range; softmax(a) == softmax(a-m) up to ~ulp.
// grid.sync()
// Phase 2: every block redundantly reduces the 1024 partials (4 KB, L2-hot,
//          identical op order -> bitwise deterministic), then broadcasts its
//          8 contiguous rows with plain dwordx4 stores (R4's proven pattern).
__global__ __launch_bounds__(256) void ca_fused(
    const float* __restrict__ e, const float* __restrict__ w,
    floatx4* __restrict__ out, float* __restrict__ partials) {
    __shared__ float exps[8];
    __shared__ float red[4];
    __shared__ float S_sh;
    const int tid  = threadIdx.x;
    const int lane = tid & 63;
    const int wv   = tid >> 6;
    const int b    = blockIdx.x;

    // ---- Phase 1: exp(tanh(e_row) . w) for 8 rows of this block ----
    const float* wr = w + lane * 8;
    const float4 w0 = *reinterpret_cast<const float4*>(wr);
    const float4 w1 = *reinterpret_cast<const float4*>(wr + 4);

    #pragma unroll
    for (int rr = 0; rr < 2; ++rr) {
        const int row = b * 8 + wv * 2 + rr;
        const float* er = e + (size_t)row * DIM + lane * 8;
        const float4 e0 = *reinterpret_cast<const float4*>(er);
        const float4 e1 = *reinterpret_cast<const float4*>(er + 4);
        float sum = tanhf(e0.x) * w0.x + tanhf(e0.y) * w0.y +
                    tanhf(e0.z) * w0.z + tanhf(e0.w) * w0.w +
                    tanhf(e1.x) * w1.x + tanhf(e1.y) * w1.y +
                    tanhf(e1.z) * w1.z + tanhf(e1.w) * w1.w;
        #pragma unroll
        for (int off = 32; off; off >>= 1) sum += __shfl_down(sum, off, 64);
        if (lane == 0) exps[wv * 2 + rr] = expf(sum);
    }
    __syncthreads();
    if (tid == 0) {
        float pa = 0.f;
        #pragma unroll
        for (int i = 0; i < 8; ++i) pa += exps[i];
        partials[b] = pa;
    }

    cg::this_grid().sync();

    // ---- Phase 2: redundant global sum (4 KB), then broadcast ----
    const floatx4 pv = reinterpret_cast<const floatx4*>(partials)[tid];
    float s = (pv.x + pv.y) + (pv.z + pv.w);
    #pragma unroll
    for (int off = 32; off; off >>= 1) s += __shfl_down(s, off, 64);
    if (lane == 0) red[wv] = s;
    __syncthreads();
    if (tid == 0) S_sh = (red[0] + red[1]) + (red[2] + red[3]);
    __syncthreads();
    const float inv = 1.0f / S_sh;

    #pragma unroll
    for (int r = 0; r < 8; ++r) {
        const float p = exps[r] * inv;
        floatx4 f;
        f.x = p; f.y = p; f.z = p; f.w = p;
        floatx4* o = out + (size_t)(b * 8 + r) * (SEQ / 4) + tid;
        #pragma unroll
        for (int k = 0; k < 8; ++k) o[k * 256] = f;
    }
}

extern "C" void kernel_launch(void* const* d_in, const int* in_sizes, int n_in,
                              void* d_out, int out_size, void* d_ws, size_t ws_size,
                              hipStream_t stream) {
    const float* enc = (const float*)d_in[0];   // [SEQ, DIM] fp32
    const float* w   = (const float*)d_in[1];   // [2*DIM] fp32 (first DIM used)
    // d_in[2] = bias: column-constant, cancels in softmax over axis 0.
    floatx4* out     = (floatx4*)d_out;         // [SEQ, SEQ] fp32
    float* partials  = (float*)d_ws;            // 1024 floats, fully rewritten

    void* args[] = {(void*)&enc, (void*)&w, (void*)&out, (void*)&partials};
    hipLaunchCooperativeKernel((const void*)ca_fused, dim3(1024), dim3(256),
                               args, 0, stream);
}

// Round 7
// 55.722 us; speedup vs baseline: 1.8400x; 1.8400x over previous
//
#include <hip/hip_runtime.h>
#include <math.h>

#define SEQ 8192
#define DIM 512  // 2*HIDDEN

typedef float floatx4 __attribute__((ext_vector_type(4)));

// Kernel A: exp_a[i] = expf( sum_d tanhf(e[i][d]) * w[d] )
// One wave (64 lanes) per row; each lane reads 8 contiguous floats (2x float4).
// Max-subtraction skipped: |a| <= sum|w| (~13 worst case), expf safely in
// fp32 range; softmax(a) == softmax(a-m) up to ~ulp.
__global__ __launch_bounds__(256) void ca_exp_a(
    const float* __restrict__ e, const float* __restrict__ w,
    float* __restrict__ exp_a) {
    const int wave = threadIdx.x >> 6;   // 0..3
    const int lane = threadIdx.x & 63;
    const int row  = blockIdx.x * 4 + wave;
    const float* er = e + (size_t)row * DIM + lane * 8;
    const float* wr = w + lane * 8;

    float4 e0 = *reinterpret_cast<const float4*>(er);
    float4 e1 = *reinterpret_cast<const float4*>(er + 4);
    float4 w0 = *reinterpret_cast<const float4*>(wr);
    float4 w1 = *reinterpret_cast<const float4*>(wr + 4);

    float sum = tanhf(e0.x) * w0.x + tanhf(e0.y) * w0.y +
                tanhf(e0.z) * w0.z + tanhf(e0.w) * w0.w +
                tanhf(e1.x) * w1.x + tanhf(e1.y) * w1.y +
                tanhf(e1.z) * w1.z + tanhf(e1.w) * w1.w;

    #pragma unroll
    for (int off = 32; off; off >>= 1) sum += __shfl_down(sum, off, 64);
    if (lane == 0) exp_a[row] = expf(sum);
}

// Kernel B: p[i] = exp_a[i] / sum(exp_a). One block; ~2 us.
__global__ __launch_bounds__(1024) void ca_normalize(
    const float* __restrict__ exp_a, float* __restrict__ p) {
    __shared__ float red[16];
    const int tid = threadIdx.x;
    const floatx4* ev = reinterpret_cast<const floatx4*>(exp_a);
    floatx4 v0 = ev[tid * 2];
    floatx4 v1 = ev[tid * 2 + 1];
    float s = ((v0.x + v0.y) + (v0.z + v0.w)) +
              ((v1.x + v1.y) + (v1.z + v1.w));
    #pragma unroll
    for (int off = 32; off; off >>= 1) s += __shfl_down(s, off, 64);
    if ((tid & 63) == 0) red[tid >> 6] = s;
    __syncthreads();
    float S = 0.f;
    #pragma unroll
    for (int i = 0; i < 16; ++i) S += red[i];
    const float inv = 1.0f / S;
    floatx4 o0, o1;
    o0.x = v0.x * inv; o0.y = v0.y * inv; o0.z = v0.z * inv; o0.w = v0.w * inv;
    o1.x = v1.x * inv; o1.y = v1.y * inv; o1.z = v1.z * inv; o1.w = v1.w * inv;
    floatx4* pv = reinterpret_cast<floatx4*>(p);
    pv[tid * 2]     = o0;
    pv[tid * 2 + 1] = o1;
}

// Kernel C: out[i][j] = p[i]. Fill-like residency: 256 blocks x 256 threads
// (~1 block/CU), each block owns 32 contiguous rows (1 MiB). All 32 uniform
// p-loads hoisted upfront (scalar loads); store loop is pure plain dwordx4.
__global__ __launch_bounds__(256) void ca_bcast(
    const float* __restrict__ p, floatx4* __restrict__ out) {
    const int t = threadIdx.x;
    const int rbase = blockIdx.x * 32;
    float pv[32];
    #pragma unroll
    for (int r = 0; r < 32; ++r) pv[r] = p[rbase + r];
    #pragma unroll
    for (int r = 0; r < 32; ++r) {
        floatx4 f;
        f.x = pv[r]; f.y = pv[r]; f.z = pv[r]; f.w = pv[r];
        floatx4* o = out + (size_t)(rbase + r) * (SEQ / 4) + t;
        #pragma unroll
        for (int k = 0; k < 8; ++k) o[k * 256] = f;
    }
}

extern "C" void kernel_launch(void* const* d_in, const int* in_sizes, int n_in,
                              void* d_out, int out_size, void* d_ws, size_t ws_size,
                              hipStream_t stream) {
    const float* enc = (const float*)d_in[0];   // [SEQ, DIM] fp32
    const float* w   = (const float*)d_in[1];   // [2*DIM] fp32 (first DIM used)
    // d_in[2] = bias: column-constant, cancels in softmax over axis 0.
    float* out = (float*)d_out;                 // [SEQ, SEQ] fp32

    float* exp_a = (float*)d_ws;                // SEQ floats
    float* p     = exp_a + SEQ;                 // SEQ floats

    ca_exp_a<<<SEQ / 4, 256, 0, stream>>>(enc, w, exp_a);
    ca_normalize<<<1, 1024, 0, stream>>>(exp_a, p);
    ca_bcast<<<256, 256, 0, stream>>>(p, (floatx4*)out);
}

// Round 8
// 53.671 us; speedup vs baseline: 1.9103x; 1.0382x over previous
//
#include <hip/hip_runtime.h>
#include <math.h>

#define SEQ 8192
#define DIM 512  // 2*HIDDEN

typedef float floatx4 __attribute__((ext_vector_type(4)));

// Kernel A: exp_a[i] = expf( sum_d tanhf(e[i][d]) * w[d] ), plus one partial
// sum per block: partials[b] = sum of this block's 4 exp values.
// One wave (64 lanes) per row; each lane reads 8 contiguous floats.
// Max-subtraction skipped: |a| <= sum|w| (~13 worst case), expf safely in
// fp32 range; softmax(a) == softmax(a-m) up to ~ulp.
__global__ __launch_bounds__(256) void ca_exp_a(
    const float* __restrict__ e, const float* __restrict__ w,
    float* __restrict__ exp_a, float* __restrict__ partials) {
    __shared__ float exps[4];
    const int wave = threadIdx.x >> 6;   // 0..3
    const int lane = threadIdx.x & 63;
    const int row  = blockIdx.x * 4 + wave;
    const float* er = e + (size_t)row * DIM + lane * 8;
    const float* wr = w + lane * 8;

    float4 e0 = *reinterpret_cast<const float4*>(er);
    float4 e1 = *reinterpret_cast<const float4*>(er + 4);
    float4 w0 = *reinterpret_cast<const float4*>(wr);
    float4 w1 = *reinterpret_cast<const float4*>(wr + 4);

    float sum = tanhf(e0.x) * w0.x + tanhf(e0.y) * w0.y +
                tanhf(e0.z) * w0.z + tanhf(e0.w) * w0.w +
                tanhf(e1.x) * w1.x + tanhf(e1.y) * w1.y +
                tanhf(e1.z) * w1.z + tanhf(e1.w) * w1.w;

    #pragma unroll
    for (int off = 32; off; off >>= 1) sum += __shfl_down(sum, off, 64);
    if (lane == 0) {
        const float ex = expf(sum);
        exp_a[row] = ex;
        exps[wave] = ex;
    }
    __syncthreads();
    if (threadIdx.x == 0)
        partials[blockIdx.x] = (exps[0] + exps[1]) + (exps[2] + exps[3]);
}

// Kernel C: out[i][j] = exp_a[i] / S. Prologue: block-local reduction of the
// 2048 partials (8 KB, L2-hot; identical op order in every block -> bitwise
// deterministic). Then R7's proven store loop: 256 blocks x 256 threads,
// 32 contiguous rows per block, plain dwordx4 stores.
__global__ __launch_bounds__(256) void ca_bcast(
    const float* __restrict__ exp_a, const float* __restrict__ partials,
    floatx4* __restrict__ out) {
    __shared__ float red[4];
    const int t    = threadIdx.x;
    const int lane = t & 63;
    const int wv   = t >> 6;

    // ---- reduce partials[0..2048) ----
    const floatx4* pvts = reinterpret_cast<const floatx4*>(partials);
    floatx4 v0 = pvts[t * 2];
    floatx4 v1 = pvts[t * 2 + 1];
    float s = ((v0.x + v0.y) + (v0.z + v0.w)) +
              ((v1.x + v1.y) + (v1.z + v1.w));
    #pragma unroll
    for (int off = 32; off; off >>= 1) s += __shfl_down(s, off, 64);
    if (lane == 0) red[wv] = s;
    __syncthreads();
    const float inv = 1.0f / ((red[0] + red[1]) + (red[2] + red[3]));

    // ---- broadcast 32 contiguous rows ----
    const int rbase = blockIdx.x * 32;
    float pv[32];
    #pragma unroll
    for (int r = 0; r < 32; ++r) pv[r] = exp_a[rbase + r] * inv;
    #pragma unroll
    for (int r = 0; r < 32; ++r) {
        floatx4 f;
        f.x = pv[r]; f.y = pv[r]; f.z = pv[r]; f.w = pv[r];
        floatx4* o = out + (size_t)(rbase + r) * (SEQ / 4) + t;
        #pragma unroll
        for (int k = 0; k < 8; ++k) o[k * 256] = f;
    }
}

extern "C" void kernel_launch(void* const* d_in, const int* in_sizes, int n_in,
                              void* d_out, int out_size, void* d_ws, size_t ws_size,
                              hipStream_t stream) {
    const float* enc = (const float*)d_in[0];   // [SEQ, DIM] fp32
    const float* w   = (const float*)d_in[1];   // [2*DIM] fp32 (first DIM used)
    // d_in[2] = bias: column-constant, cancels in softmax over axis 0.
    float* out = (float*)d_out;                 // [SEQ, SEQ] fp32

    float* exp_a    = (float*)d_ws;             // SEQ floats, fully rewritten
    float* partials = exp_a + SEQ;              // 2048 floats, fully rewritten

    ca_exp_a<<<SEQ / 4, 256, 0, stream>>>(enc, w, exp_a, partials);
    ca_bcast<<<256, 256, 0, stream>>>(exp_a, partials, (floatx4*)out);
}

// Round 9
// 52.906 us; speedup vs baseline: 1.9379x; 1.0145x over previous
//
#include <hip/hip_runtime.h>
#include <math.h>

#define SEQ 8192
#define DIM 512  // 2*HIDDEN

typedef float floatx4 __attribute__((ext_vector_type(4)));

// Kernel A: exp_a[i] = expf( sum_d tanhf(e[i][d]) * w[d] ), plus one partial
// sum per block: partials[b] = sum of this block's 4 exp values.
// Max-subtraction skipped: |a| <= sum|w| (~13 worst case), expf safely in
// fp32 range; softmax(a) == softmax(a-m) up to ~ulp.
__global__ __launch_bounds__(256) void ca_exp_a(
    const float* __restrict__ e, const float* __restrict__ w,
    float* __restrict__ exp_a, float* __restrict__ partials) {
    __shared__ float exps[4];
    const int wave = threadIdx.x >> 6;   // 0..3
    const int lane = threadIdx.x & 63;
    const int row  = blockIdx.x * 4 + wave;
    const float* er = e + (size_t)row * DIM + lane * 8;
    const float* wr = w + lane * 8;

    float4 e0 = *reinterpret_cast<const float4*>(er);
    float4 e1 = *reinterpret_cast<const float4*>(er + 4);
    float4 w0 = *reinterpret_cast<const float4*>(wr);
    float4 w1 = *reinterpret_cast<const float4*>(wr + 4);

    float sum = tanhf(e0.x) * w0.x + tanhf(e0.y) * w0.y +
                tanhf(e0.z) * w0.z + tanhf(e0.w) * w0.w +
                tanhf(e1.x) * w1.x + tanhf(e1.y) * w1.y +
                tanhf(e1.z) * w1.z + tanhf(e1.w) * w1.w;

    #pragma unroll
    for (int off = 32; off; off >>= 1) sum += __shfl_down(sum, off, 64);
    if (lane == 0) {
        const float ex = expf(sum);
        exp_a[row] = ex;
        exps[wave] = ex;
    }
    __syncthreads();
    if (threadIdx.x == 0)
        partials[blockIdx.x] = (exps[0] + exps[1]) + (exps[2] + exps[3]);
}

// Kernel C: out[i][j] = exp_a[i] / S. Prologue: block-local reduction of the
// 2048 partials (8 KB, L2-hot; identical op order in every block -> bitwise
// deterministic). Store phase: ROUND-ROBIN row assignment — block b owns rows
// {b + 256r : r=0..31}, so at iteration r the 256 lockstep blocks together
// write rows [256r, 256r+256) = one contiguous 8 MiB window sweeping the
// buffer (fillBuffer's time-localized write pattern). Plain dwordx4 stores.
__global__ __launch_bounds__(256) void ca_bcast(
    const float* __restrict__ exp_a, const float* __restrict__ partials,
    floatx4* __restrict__ out) {
    __shared__ float red[4];
    const int t    = threadIdx.x;
    const int lane = t & 63;
    const int wv   = t >> 6;

    // ---- reduce partials[0..2048) ----
    const floatx4* pvts = reinterpret_cast<const floatx4*>(partials);
    floatx4 v0 = pvts[t * 2];
    floatx4 v1 = pvts[t * 2 + 1];
    float s = ((v0.x + v0.y) + (v0.z + v0.w)) +
              ((v1.x + v1.y) + (v1.z + v1.w));
    #pragma unroll
    for (int off = 32; off; off >>= 1) s += __shfl_down(s, off, 64);
    if (lane == 0) red[wv] = s;
    __syncthreads();
    const float inv = 1.0f / ((red[0] + red[1]) + (red[2] + red[3]));

    // ---- broadcast 32 round-robin rows ----
    const int b = blockIdx.x;            // rows b, b+256, ..., b+256*31
    float pv[32];
    #pragma unroll
    for (int r = 0; r < 32; ++r) pv[r] = exp_a[b + r * 256] * inv;
    #pragma unroll
    for (int r = 0; r < 32; ++r) {
        floatx4 f;
        f.x = pv[r]; f.y = pv[r]; f.z = pv[r]; f.w = pv[r];
        floatx4* o = out + (size_t)(b + r * 256) * (SEQ / 4) + t;
        #pragma unroll
        for (int k = 0; k < 8; ++k) o[k * 256] = f;
    }
}

extern "C" void kernel_launch(void* const* d_in, const int* in_sizes, int n_in,
                              void* d_out, int out_size, void* d_ws, size_t ws_size,
                              hipStream_t stream) {
    const float* enc = (const float*)d_in[0];   // [SEQ, DIM] fp32
    const float* w   = (const float*)d_in[1];   // [2*DIM] fp32 (first DIM used)
    // d_in[2] = bias: column-constant, cancels in softmax over axis 0.
    float* out = (float*)d_out;                 // [SEQ, SEQ] fp32

    float* exp_a    = (float*)d_ws;             // SEQ floats, fully rewritten
    float* partials = exp_a + SEQ;              // 2048 floats, fully rewritten

    ca_exp_a<<<SEQ / 4, 256, 0, stream>>>(enc, w, exp_a, partials);
    ca_bcast<<<256, 256, 0, stream>>>(exp_a, partials, (floatx4*)out);
}